// Round 4
// baseline (143.337 us; speedup 1.0000x reference)
//
#include <hip/hip_runtime.h>
#include <stdint.h>

// LowRankConv2d: out[b,o,h,w] = (1/9)*sum_{k,r,c} Hm[k,o,r]*G[k,r,c]*x[b,c,h+i-1,w+j-1] + bias[o]
// R9: R7 base (XCD remaps reverted: R6/R8 showed no producer->consumer locality win --
//     shared memory-side LLC already absorbs T9). ONE change: k_fused1 software pipeline:
//     LDS double-buffer xs[2] + register prefetch of next item's x (f32x4 x4 per thread
//     for unit tid, +4 for unit tid+384 on tid<128). Next item's loads issue BEFORE this
//     item's MFMA phase; cvt+ds_write after; ONE sync per item (was 2). Bf loaded
//     4-at-a-time to keep VGPR under the (384,3) cap so prefetch regs don't spill.

#define BATCH 16
#define CIN   256
#define COUT  256
#define RANK  32
#define HH    56
#define WW    56
#define SP    (HH*WW)        // 3136
#define YP    58
#define XP    58
#define PCELL (YP*XP)        // 3364
#define PLANE (BATCH*PCELL)

typedef __bf16 bf16x8 __attribute__((ext_vector_type(8)));
typedef __bf16 bf16x4 __attribute__((ext_vector_type(4)));
typedef float  f32x4  __attribute__((ext_vector_type(4)));

// ws layout (bytes):
//  T9   [9][16][58][58][32] bf16  = 31,002,624
//  G_bf [288][256] bf16           = 147,456
//  Hm_bf[9][256][32] bf16         = 147,456
#define OFF_T9 0
#define OFF_GB 31002624
#define OFF_HB (OFF_GB + 147456)

#define RING_U4 (9 * 16 * 228 * 4)   // border cells * 64B(=4 uint4)
#define PREP_N  (147456 + RING_U4)   // 278,784

__device__ __forceinline__ uint16_t bfbits(float f) {
  __bf16 h = (__bf16)f;
  return __builtin_bit_cast(uint16_t, h);
}

// weight casts + T9 border ring zero, one launch
__global__ __launch_bounds__(256) void k_prep(const float* __restrict__ G,
                                              const float* __restrict__ Hm,
                                              uint16_t* __restrict__ G_bf,
                                              uint16_t* __restrict__ Hm_bf,
                                              uint16_t* __restrict__ T9) {
  int i = blockIdx.x * 256 + threadIdx.x;
  if (i < 73728)  { G_bf[i] = bfbits(G[i]); return; }
  if (i < 147456) { Hm_bf[i - 73728] = bfbits(Hm[i - 73728]); return; }
  int j = i - 147456;
  if (j >= RING_U4) return;
  int v = j & 3, cell = j >> 2;
  int tb = cell / 228, c = cell % 228;
  int y, xx;
  if      (c < 58)  { y = 0;       xx = c;       }
  else if (c < 116) { y = 57;      xx = c - 58;  }
  else if (c < 172) { y = c - 115; xx = 0;       }
  else              { y = c - 171; xx = 57;      }
  uint16_t* base = T9 + ((size_t)tb * PCELL + y * XP + xx) * 32;
  uint4 z; z.x = z.y = z.z = z.w = 0u;
  ((uint4*)base)[v] = z;
}

// Fused transpose+cast+stage1: T9[tap][cell][r] = sum_c G[tap*32+r][c] * x[b][c][s]
// Block: 384 thr (6 waves); wave w holds G rows 48w..48w+47 reg-resident (24 frags).
// Pipelined persistent loop (items bid, bid+512, ...): prefetch next item's x into
// registers before this item's MFMA phase, cvt+ds_write into the other LDS buffer
// after, one __syncthreads per item. Unit tid covers (s4=tid&7, c0=(tid>>3)*4);
// unit tid+384 (tid<128) covers the remaining 128 of 512 staging units.
__global__ __launch_bounds__(384, 3) void k_fused1(const float* __restrict__ x,
                                                   const uint16_t* __restrict__ G_bf,
                                                   uint16_t* __restrict__ T9) {
  __shared__ uint16_t xs[2][32 * 264];
  const int tid = threadIdx.x;
  const int wave = tid >> 6, lane = tid & 63;
  const int q = lane >> 4, t = lane & 15;

  const int u0s4 = tid & 7,        u0c0 = (tid >> 3) * 4;
  const int u1s4 = (tid + 384) & 7, u1c0 = ((tid + 384) >> 3) * 4;
  const bool has_u1 = (tid < 128);

  bf16x8 A[3][8];
  {
    const uint16_t* gb = G_bf + (size_t)(wave * 48 + t) * CIN + q * 8;
#pragma unroll
    for (int i = 0; i < 3; ++i)
#pragma unroll
      for (int ks = 0; ks < 8; ++ks)
        A[i][ks] = *(const bf16x8*)(gb + (size_t)i * 16 * CIN + ks * 32);
  }

  f32x4 f0[4], f1[4];

  // prologue: load + stage item0 into xs[0]
  int item = blockIdx.x;
  {
    const int b = item / 98, ch = item - b * 98;
    const float* xr0 = x + ((size_t)(b * CIN + u0c0)) * SP + ch * 32 + u0s4 * 4;
#pragma unroll
    for (int e = 0; e < 4; ++e) f0[e] = *(const f32x4*)(xr0 + (size_t)e * SP);
    if (has_u1) {
      const float* xr1 = x + ((size_t)(b * CIN + u1c0)) * SP + ch * 32 + u1s4 * 4;
#pragma unroll
      for (int e = 0; e < 4; ++e) f1[e] = *(const f32x4*)(xr1 + (size_t)e * SP);
    }
#pragma unroll
    for (int p = 0; p < 4; ++p) {
      bf16x4 v;
#pragma unroll
      for (int e = 0; e < 4; ++e) ((__bf16*)&v)[e] = (__bf16)f0[e][p];
      *(bf16x4*)&xs[0][(u0s4 * 4 + p) * 264 + u0c0] = v;
    }
    if (has_u1) {
#pragma unroll
      for (int p = 0; p < 4; ++p) {
        bf16x4 v;
#pragma unroll
        for (int e = 0; e < 4; ++e) ((__bf16*)&v)[e] = (__bf16)f1[e][p];
        *(bf16x4*)&xs[0][(u1s4 * 4 + p) * 264 + u1c0] = v;
      }
    }
  }
  __syncthreads();

  int cur = 0;
#pragma unroll 1
  for (; item < 1568; item += 512) {
    const int nxt = item + 512;

    // issue next item's loads (block-uniform branch; waits happen at cvt, after compute)
    if (nxt < 1568) {
      const int bn = nxt / 98, chn = nxt - bn * 98;
      const float* xr0 = x + ((size_t)(bn * CIN + u0c0)) * SP + chn * 32 + u0s4 * 4;
#pragma unroll
      for (int e = 0; e < 4; ++e) f0[e] = *(const f32x4*)(xr0 + (size_t)e * SP);
      if (has_u1) {
        const float* xr1 = x + ((size_t)(bn * CIN + u1c0)) * SP + chn * 32 + u1s4 * 4;
#pragma unroll
        for (int e = 0; e < 4; ++e) f1[e] = *(const f32x4*)(xr1 + (size_t)e * SP);
      }
    }

    // compute current item from xs[cur]
    const int b = item / 98, ch = item - b * 98;
    const uint16_t* xb = xs[cur];
#pragma unroll 1
    for (int nt = 0; nt < 2; ++nt) {
      f32x4 acc[3];
#pragma unroll
      for (int i = 0; i < 3; ++i) acc[i] = (f32x4){0.f, 0.f, 0.f, 0.f};
#pragma unroll
      for (int kh = 0; kh < 2; ++kh) {
        bf16x8 Bf[4];
#pragma unroll
        for (int k4 = 0; k4 < 4; ++k4)
          Bf[k4] = *(const bf16x8*)&xb[(nt * 16 + t) * 264 + (kh * 4 + k4) * 32 + q * 8];
#pragma unroll
        for (int k4 = 0; k4 < 4; ++k4)
#pragma unroll
          for (int i = 0; i < 3; ++i)
            acc[i] = __builtin_amdgcn_mfma_f32_16x16x32_bf16(A[i][kh * 4 + k4], Bf[k4],
                                                             acc[i], 0, 0, 0);
      }

      const int p = ch * 32 + nt * 16 + t;          // lane's store cell (D col = t)
      const int h = p / WW, w = p - (p / WW) * WW;
      const size_t cellbase = ((size_t)b * PCELL + (h + 1) * XP + (w + 1)) * 32;
#pragma unroll
      for (int i = 0; i < 3; ++i) {
        const int kr0 = wave * 48 + i * 16 + q * 4; // 4-run stays within one tap (4|32)
        const int tap = kr0 >> 5, r = kr0 & 31;
        uint2 pv;
        pv.x = (uint32_t)bfbits(acc[i][0]) | ((uint32_t)bfbits(acc[i][1]) << 16);
        pv.y = (uint32_t)bfbits(acc[i][2]) | ((uint32_t)bfbits(acc[i][3]) << 16);
        *(uint2*)(T9 + (size_t)tap * PLANE * 32 + cellbase + r) = pv;
      }
    }

    // cvt + stage next item into the other buffer (vmcnt waits land here, post-compute)
    if (nxt < 1568) {
      uint16_t* xw = xs[cur ^ 1];
#pragma unroll
      for (int p = 0; p < 4; ++p) {
        bf16x4 v;
#pragma unroll
        for (int e = 0; e < 4; ++e) ((__bf16*)&v)[e] = (__bf16)f0[e][p];
        *(bf16x4*)&xw[(u0s4 * 4 + p) * 264 + u0c0] = v;
      }
      if (has_u1) {
#pragma unroll
        for (int p = 0; p < 4; ++p) {
          bf16x4 v;
#pragma unroll
          for (int e = 0; e < 4; ++e) ((__bf16*)&v)[e] = (__bf16)f1[e][p];
          *(bf16x4*)&xw[(u1s4 * 4 + p) * 264 + u1c0] = v;
        }
      }
    }
    __syncthreads();
    cur ^= 1;
  }
}

// Stage 2: out[p][o] = (1/9)*sum_tap sum_r T9[tap][cell(p)+shift][r]*Hm[tap][o][r] + bias[o]
// Block: 512 thr (8 waves); wave w owns o in [32w, 32w+32): Bf[9][2] reg-resident (72 VGPR)
// -> 16 waves/CU. All 8 waves read identical T9 A-tiles (L1-shared). Persistent grid 512.
__global__ __launch_bounds__(512, 4) void k_stage2(const uint16_t* __restrict__ T9,
                                                   const uint16_t* __restrict__ Hm_bf,
                                                   const float* __restrict__ bias,
                                                   float* __restrict__ out) {
  const int wave = threadIdx.x >> 6, lane = threadIdx.x & 63;
  const int q = lane >> 4, t = lane & 15;

  bf16x8 Bf[9][2];
  float bv[2];
#pragma unroll
  for (int j = 0; j < 2; ++j) {
    const int o = wave * 32 + j * 16 + t;
    bv[j] = bias[o];
#pragma unroll
    for (int tap = 0; tap < 9; ++tap)
      Bf[tap][j] = *(const bf16x8*)(Hm_bf + ((size_t)(tap * COUT + o)) * RANK + q * 8);
  }

#pragma unroll 1
  for (int mt = blockIdx.x; mt < 3136; mt += 512) {
    const int p0 = mt * 16;
    const int b = p0 / SP, s0 = p0 - b * SP;
    const int sa = s0 + t;
    const int ha = sa / WW, wa = sa - ha * WW;
    const uint16_t* abase = T9 + ((size_t)(b * PCELL + ha * XP + wa)) * 32 + q * 8;

    f32x4 acc[2];
    acc[0] = (f32x4){0.f, 0.f, 0.f, 0.f};
    acc[1] = (f32x4){0.f, 0.f, 0.f, 0.f};
#pragma unroll
    for (int tap = 0; tap < 9; ++tap) {
      const int di = tap / 3, dj = tap % 3;
      bf16x8 af = *(const bf16x8*)(abase + (size_t)tap * PLANE * 32 + (di * XP + dj) * 32);
      acc[0] = __builtin_amdgcn_mfma_f32_16x16x32_bf16(af, Bf[0 + tap][0], acc[0], 0, 0, 0);
      acc[1] = __builtin_amdgcn_mfma_f32_16x16x32_bf16(af, Bf[0 + tap][1], acc[1], 0, 0, 0);
    }

    const int sd = s0 + q * 4;                      // D rows = 4 consecutive positions
#pragma unroll
    for (int j = 0; j < 2; ++j) {
      const int o = wave * 32 + j * 16 + t;
      f32x4 v = acc[j] * (1.0f / 9.0f) + bv[j];
      *(f32x4*)(out + ((size_t)(b * COUT + o)) * SP + sd) = v;
    }
  }
}

extern "C" void kernel_launch(void* const* d_in, const int* in_sizes, int n_in,
                              void* d_out, int out_size, void* d_ws, size_t ws_size,
                              hipStream_t stream) {
  const float* x    = (const float*)d_in[0];
  const float* G    = (const float*)d_in[1];
  const float* Hm   = (const float*)d_in[2];
  const float* bias = (const float*)d_in[3];
  float* out = (float*)d_out;
  char* ws = (char*)d_ws;

  uint16_t* T9    = (uint16_t*)(ws + OFF_T9);
  uint16_t* G_bf  = (uint16_t*)(ws + OFF_GB);
  uint16_t* Hm_bf = (uint16_t*)(ws + OFF_HB);

  k_prep<<<PREP_N / 256, 256, 0, stream>>>(G, Hm, G_bf, Hm_bf, T9);
  k_fused1<<<512, 384, 0, stream>>>(x, G_bf, T9);
  k_stage2<<<512, 512, 0, stream>>>(T9, Hm_bf, bias, out);
}

// Round 5
// 137.445 us; speedup vs baseline: 1.0429x; 1.0429x over previous
//
#include <hip/hip_runtime.h>
#include <stdint.h>

// LowRankConv2d: out[b,o,h,w] = (1/9)*sum_{k,r,c} Hm[k,o,r]*G[k,r,c]*x[b,c,h+i-1,w+j-1] + bias[o]
// R10: MEASUREMENT ROUND. Exact R7 kernels (the 137.3us best) with ONE change:
//      k_fused1 and k_stage2 grids halved 512->256 (work/block doubled, same math).
//      Purpose: push both kernels' dispatch durations above the ~41us fill threshold so
//      they appear in the rocprof top-5 WITH their counters (MfmaUtil/VALUBusy/FETCH/
//      WRITE/bank-conflicts) and exact per-kernel durations. R6/R8/R9 structural theories
//      all regressed; this round buys the ablation data to aim the next change.
//      Next round reverts to grid 512 + applies the indicated fix.

#define BATCH 16
#define CIN   256
#define COUT  256
#define RANK  32
#define HH    56
#define WW    56
#define SP    (HH*WW)        // 3136
#define YP    58
#define XP    58
#define PCELL (YP*XP)        // 3364
#define PLANE (BATCH*PCELL)

typedef __bf16 bf16x8 __attribute__((ext_vector_type(8)));
typedef __bf16 bf16x4 __attribute__((ext_vector_type(4)));
typedef float  f32x4  __attribute__((ext_vector_type(4)));

// ws layout (bytes):
//  T9   [9][16][58][58][32] bf16  = 31,002,624
//  G_bf [288][256] bf16           = 147,456
//  Hm_bf[9][256][32] bf16         = 147,456
#define OFF_T9 0
#define OFF_GB 31002624
#define OFF_HB (OFF_GB + 147456)

#define RING_U4 (9 * 16 * 228 * 4)   // border cells * 64B(=4 uint4)
#define PREP_N  (147456 + RING_U4)   // 278,784

__device__ __forceinline__ uint16_t bfbits(float f) {
  __bf16 h = (__bf16)f;
  return __builtin_bit_cast(uint16_t, h);
}

// weight casts + T9 border ring zero, one launch
__global__ __launch_bounds__(256) void k_prep(const float* __restrict__ G,
                                              const float* __restrict__ Hm,
                                              uint16_t* __restrict__ G_bf,
                                              uint16_t* __restrict__ Hm_bf,
                                              uint16_t* __restrict__ T9) {
  int i = blockIdx.x * 256 + threadIdx.x;
  if (i < 73728)  { G_bf[i] = bfbits(G[i]); return; }
  if (i < 147456) { Hm_bf[i - 73728] = bfbits(Hm[i - 73728]); return; }
  int j = i - 147456;
  if (j >= RING_U4) return;
  int v = j & 3, cell = j >> 2;
  int tb = cell / 228, c = cell % 228;
  int y, xx;
  if      (c < 58)  { y = 0;       xx = c;       }
  else if (c < 116) { y = 57;      xx = c - 58;  }
  else if (c < 172) { y = c - 115; xx = 0;       }
  else              { y = c - 171; xx = 57;      }
  uint16_t* base = T9 + ((size_t)tb * PCELL + y * XP + xx) * 32;
  uint4 z; z.x = z.y = z.z = z.w = 0u;
  ((uint4*)base)[v] = z;
}

// Fused transpose+cast+stage1: T9[tap][cell][r] = sum_c G[tap*32+r][c] * x[b][c][s]
// Block: 384 thr (6 waves); wave w holds G rows 48w..48w+47 reg-resident (24 frags).
// Per item (b, 32-pos chunk): stage x into LDS bf16 [32 s][264 c-padded] via f32x4
// loads (unit = 4 positions x 4 c-rows), then 2 n-tiles of 16 pos: 8x ds_read_b128
// B-frags, 24 MFMA, 3 uint2 stores per wave.  [R10: grid 256, 6.125 items/block]
__global__ __launch_bounds__(384, 3) void k_fused1(const float* __restrict__ x,
                                                   const uint16_t* __restrict__ G_bf,
                                                   uint16_t* __restrict__ T9) {
  __shared__ uint16_t xs[32 * 264];
  const int tid = threadIdx.x;
  const int wave = tid >> 6, lane = tid & 63;
  const int q = lane >> 4, t = lane & 15;

  bf16x8 A[3][8];
  {
    const uint16_t* gb = G_bf + (size_t)(wave * 48 + t) * CIN + q * 8;
#pragma unroll
    for (int i = 0; i < 3; ++i)
#pragma unroll
      for (int ks = 0; ks < 8; ++ks)
        A[i][ks] = *(const bf16x8*)(gb + (size_t)i * 16 * CIN + ks * 32);
  }

#pragma unroll 1
  for (int item = blockIdx.x; item < 1568; item += 256) {
    const int b = item / 98, ch = item - b * 98;    // 98 chunks of 32 positions per batch

    // stage: 512 units = (s4 0..7, c4 0..63); unit loads 4 c-rows as f32x4 (4 positions
    // each, 16B coalesced), repacks to 4x bf16x4 (one per position), writes 8B each.
#pragma unroll 1
    for (int u = tid; u < 512; u += 384) {
      const int s4 = u & 7, c4 = u >> 3;
      const int c0 = c4 * 4;
      const float* xr = x + ((size_t)(b * CIN + c0)) * SP + ch * 32 + s4 * 4;
      f32x4 f[4];
#pragma unroll
      for (int e = 0; e < 4; ++e)
        f[e] = *(const f32x4*)(xr + (size_t)e * SP);
#pragma unroll
      for (int p = 0; p < 4; ++p) {
        bf16x4 v;
#pragma unroll
        for (int e = 0; e < 4; ++e)
          ((__bf16*)&v)[e] = (__bf16)f[e][p];
        *(bf16x4*)&xs[(s4 * 4 + p) * 264 + c0] = v;
      }
    }
    __syncthreads();

#pragma unroll 1
    for (int nt = 0; nt < 2; ++nt) {
      bf16x8 Bf[8];
#pragma unroll
      for (int ks = 0; ks < 8; ++ks)
        Bf[ks] = *(const bf16x8*)&xs[(nt * 16 + t) * 264 + ks * 32 + q * 8];

      f32x4 acc[3];
#pragma unroll
      for (int i = 0; i < 3; ++i) acc[i] = (f32x4){0.f, 0.f, 0.f, 0.f};
#pragma unroll
      for (int ks = 0; ks < 8; ++ks)
#pragma unroll
        for (int i = 0; i < 3; ++i)
          acc[i] = __builtin_amdgcn_mfma_f32_16x16x32_bf16(A[i][ks], Bf[ks], acc[i], 0, 0, 0);

      const int p = ch * 32 + nt * 16 + t;          // lane's store cell (D col = t)
      const int h = p / WW, w = p - (p / WW) * WW;
      const size_t cellbase = ((size_t)b * PCELL + (h + 1) * XP + (w + 1)) * 32;
#pragma unroll
      for (int i = 0; i < 3; ++i) {
        const int kr0 = wave * 48 + i * 16 + q * 4; // 4-run stays within one tap (4|32)
        const int tap = kr0 >> 5, r = kr0 & 31;
        uint2 pv;
        pv.x = (uint32_t)bfbits(acc[i][0]) | ((uint32_t)bfbits(acc[i][1]) << 16);
        pv.y = (uint32_t)bfbits(acc[i][2]) | ((uint32_t)bfbits(acc[i][3]) << 16);
        *(uint2*)(T9 + (size_t)tap * PLANE * 32 + cellbase + r) = pv;
      }
    }
    __syncthreads();
  }
}

// Stage 2: out[p][o] = (1/9)*sum_tap sum_r T9[tap][cell(p)+shift][r]*Hm[tap][o][r] + bias[o]
// Block: 512 thr (8 waves); wave w owns o in [32w, 32w+32): Bf[9][2] reg-resident (72 VGPR).
// All 8 waves read identical T9 A-tiles (L1-shared).  [R10: grid 256, 12.25 tiles/block]
__global__ __launch_bounds__(512, 4) void k_stage2(const uint16_t* __restrict__ T9,
                                                   const uint16_t* __restrict__ Hm_bf,
                                                   const float* __restrict__ bias,
                                                   float* __restrict__ out) {
  const int wave = threadIdx.x >> 6, lane = threadIdx.x & 63;
  const int q = lane >> 4, t = lane & 15;

  bf16x8 Bf[9][2];
  float bv[2];
#pragma unroll
  for (int j = 0; j < 2; ++j) {
    const int o = wave * 32 + j * 16 + t;
    bv[j] = bias[o];
#pragma unroll
    for (int tap = 0; tap < 9; ++tap)
      Bf[tap][j] = *(const bf16x8*)(Hm_bf + ((size_t)(tap * COUT + o)) * RANK + q * 8);
  }

#pragma unroll 1
  for (int mt = blockIdx.x; mt < 3136; mt += 256) {
    const int p0 = mt * 16;
    const int b = p0 / SP, s0 = p0 - b * SP;
    const int sa = s0 + t;
    const int ha = sa / WW, wa = sa - ha * WW;
    const uint16_t* abase = T9 + ((size_t)(b * PCELL + ha * XP + wa)) * 32 + q * 8;

    f32x4 acc[2];
    acc[0] = (f32x4){0.f, 0.f, 0.f, 0.f};
    acc[1] = (f32x4){0.f, 0.f, 0.f, 0.f};
#pragma unroll
    for (int tap = 0; tap < 9; ++tap) {
      const int di = tap / 3, dj = tap % 3;
      bf16x8 af = *(const bf16x8*)(abase + (size_t)tap * PLANE * 32 + (di * XP + dj) * 32);
      acc[0] = __builtin_amdgcn_mfma_f32_16x16x32_bf16(af, Bf[0 + tap][0], acc[0], 0, 0, 0);
      acc[1] = __builtin_amdgcn_mfma_f32_16x16x32_bf16(af, Bf[0 + tap][1], acc[1], 0, 0, 0);
    }

    const int sd = s0 + q * 4;                      // D rows = 4 consecutive positions
#pragma unroll
    for (int j = 0; j < 2; ++j) {
      const int o = wave * 32 + j * 16 + t;
      f32x4 v = acc[j] * (1.0f / 9.0f) + bv[j];
      *(f32x4*)(out + ((size_t)(b * COUT + o)) * SP + sd) = v;
    }
  }
}

extern "C" void kernel_launch(void* const* d_in, const int* in_sizes, int n_in,
                              void* d_out, int out_size, void* d_ws, size_t ws_size,
                              hipStream_t stream) {
  const float* x    = (const float*)d_in[0];
  const float* G    = (const float*)d_in[1];
  const float* Hm   = (const float*)d_in[2];
  const float* bias = (const float*)d_in[3];
  float* out = (float*)d_out;
  char* ws = (char*)d_ws;

  uint16_t* T9    = (uint16_t*)(ws + OFF_T9);
  uint16_t* G_bf  = (uint16_t*)(ws + OFF_GB);
  uint16_t* Hm_bf = (uint16_t*)(ws + OFF_HB);

  k_prep<<<PREP_N / 256, 256, 0, stream>>>(G, Hm, G_bf, Hm_bf, T9);
  k_fused1<<<256, 384, 0, stream>>>(x, G_bf, T9);
  k_stage2<<<256, 512, 0, stream>>>(T9, Hm_bf, bias, out);
}